// Round 1
// baseline (249.835 us; speedup 1.0000x reference)
//
#include <hip/hip_runtime.h>
#include <hip/hip_bf16.h>

// CLIP loss: B=8192, D=1024, temp=0.5.
// loss = mean_i [ 0.5*(log sum_j exp(s_ij) + log sum_j exp(s_ji)) - s_ii ]
// where s = (zi_n @ zj_n^T) * 2.  |s| <= 2 so exp never overflows -> no max trick.
//
// ws layout (bytes):
//   [0,16M)        zi_bf16 (x2 temperature folded in)
//   [16M,32M)      zj_bf16
//   [32M,34M)      rp[64][8192]  row-sum partials (tile-col bj major)
//   [34M,36M)      cp[64][8192]  col-sum partials (tile-row bi major)
//   [36M,36M+32K)  diag[8192]
//   [+32K,+32K+128) block partials for final reduce

using short8 = __attribute__((ext_vector_type(8))) short;
using f32x4  = __attribute__((ext_vector_type(4))) float;

__device__ __forceinline__ unsigned short f2bf(float f) {
    unsigned int u = __float_as_uint(f);
    unsigned int r = (u + 0x7FFFu + ((u >> 16) & 1u)) >> 16;
    return (unsigned short)r;
}

__device__ __forceinline__ void async16(const unsigned short* g, unsigned short* l) {
    __builtin_amdgcn_global_load_lds(
        (const __attribute__((address_space(1))) void*)g,
        (__attribute__((address_space(3))) void*)l, 16, 0, 0);
}

// ---- kernel 1: row-normalize fp32 -> bf16 bits, with extra scale folded ----
__global__ __launch_bounds__(256) void clip_norm_k(const float* __restrict__ in,
                                                   unsigned short* __restrict__ out,
                                                   float extra) {
    int row = blockIdx.x;
    const float4* ip = reinterpret_cast<const float4*>(in + (size_t)row * 1024);
    float4 v = ip[threadIdx.x];
    float ss = v.x * v.x + v.y * v.y + v.z * v.z + v.w * v.w;
    #pragma unroll
    for (int o = 1; o < 64; o <<= 1) ss += __shfl_xor(ss, o);
    __shared__ float sb[4];
    if ((threadIdx.x & 63) == 0) sb[threadIdx.x >> 6] = ss;
    __syncthreads();
    float tot = sb[0] + sb[1] + sb[2] + sb[3];
    float scl = extra / fmaxf(sqrtf(tot), 1e-12f);
    ushort4 o4;
    o4.x = f2bf(v.x * scl);
    o4.y = f2bf(v.y * scl);
    o4.z = f2bf(v.z * scl);
    o4.w = f2bf(v.w * scl);
    *reinterpret_cast<ushort4*>(out + (size_t)row * 1024 + threadIdx.x * 4) = o4;
}

// ---- kernel 2: 128x128-tile bf16 MFMA GEMM + fused exp row/col sums ----
// grid 4096 = 64x64 tiles; 256 threads = 4 waves in 2x2; per-wave 64x64 out.
__global__ __launch_bounds__(256) void clip_gemm_k(
    const unsigned short* __restrict__ A,   // zi_bf [8192][1024]
    const unsigned short* __restrict__ Bm,  // zj_bf [8192][1024]
    float* __restrict__ rp, float* __restrict__ cp, float* __restrict__ dg) {
    __shared__ unsigned short As[128 * 64];
    __shared__ unsigned short Bs[128 * 64];
    __shared__ float rbuf[2][128];
    __shared__ float cbuf[2][128];

    const int blk = blockIdx.x;
    const int bi = blk >> 6, bj = blk & 63;
    const int tid = threadIdx.x;
    const int l = tid & 63, w = tid >> 6;
    const int wm = w >> 1, wn = w & 1;
    const int lhi = l >> 4, llo = l & 15;

    f32x4 acc[4][4] = {};

    const unsigned short* Ag = A + (size_t)(bi * 128) * 1024;
    const unsigned short* Bg = Bm + (size_t)(bj * 128) * 1024;

    for (int kt = 0; kt < 1024; kt += 64) {
        // stage 128x64 A-tile + B-tile, 16 KB each, linear LDS, 16B/lane
        #pragma unroll
        for (int q = 0; q < 4; ++q) {
            int L = q * 256 + tid;
            int row = L >> 3, ch = L & 7;
            async16(Ag + (size_t)row * 1024 + kt + ch * 8, &As[q * 2048 + w * 512]);
            async16(Bg + (size_t)row * 1024 + kt + ch * 8, &Bs[q * 2048 + w * 512]);
        }
        __syncthreads();
        #pragma unroll
        for (int kk = 0; kk < 64; kk += 32) {
            short8 af[4], bf_[4];
            #pragma unroll
            for (int m = 0; m < 4; ++m) {
                int row = wm * 64 + m * 16 + llo;
                af[m] = *reinterpret_cast<const short8*>(&As[row * 64 + kk + lhi * 8]);
            }
            #pragma unroll
            for (int n = 0; n < 4; ++n) {
                int row = wn * 64 + n * 16 + llo;
                bf_[n] = *reinterpret_cast<const short8*>(&Bs[row * 64 + kk + lhi * 8]);
            }
            #pragma unroll
            for (int m = 0; m < 4; ++m)
                #pragma unroll
                for (int n = 0; n < 4; ++n)
                    acc[m][n] = __builtin_amdgcn_mfma_f32_16x16x32_bf16(
                        af[m], bf_[n], acc[m][n], 0, 0, 0);
        }
        __syncthreads();
    }

    // D layout (verified m89/m91): col = l&15, row = (l>>4)*4 + reg
    // diagonal of sim (before exp)
    if (bi == bj && wm == wn) {
        #pragma unroll
        for (int m = 0; m < 4; ++m)
            #pragma unroll
            for (int r = 0; r < 4; ++r)
                if (lhi * 4 + r == llo)
                    dg[bi * 128 + wm * 64 + m * 16 + llo] = acc[m][m][r];
    }

    // exp in place (|s|<=2: safe, no max-subtraction)
    #pragma unroll
    for (int m = 0; m < 4; ++m)
        #pragma unroll
        for (int n = 0; n < 4; ++n)
            #pragma unroll
            for (int r = 0; r < 4; ++r)
                acc[m][n][r] = exp2f(acc[m][n][r] * 1.44269504f);

    // row sums over this wave's 64 cols: reduce across llo (lanes 0-15 group)
    #pragma unroll
    for (int m = 0; m < 4; ++m) {
        #pragma unroll
        for (int r = 0; r < 4; ++r) {
            float v = acc[m][0][r] + acc[m][1][r] + acc[m][2][r] + acc[m][3][r];
            v += __shfl_xor(v, 1);
            v += __shfl_xor(v, 2);
            v += __shfl_xor(v, 4);
            v += __shfl_xor(v, 8);
            if (llo == 0) rbuf[wn][wm * 64 + m * 16 + lhi * 4 + r] = v;
        }
    }
    // col sums over this wave's 64 rows: reduce across lhi groups
    #pragma unroll
    for (int n = 0; n < 4; ++n) {
        float v = 0.f;
        #pragma unroll
        for (int m = 0; m < 4; ++m)
            v += acc[m][n][0] + acc[m][n][1] + acc[m][n][2] + acc[m][n][3];
        v += __shfl_xor(v, 16);
        v += __shfl_xor(v, 32);
        if (lhi == 0) cbuf[wm][wn * 64 + n * 16 + llo] = v;
    }
    __syncthreads();
    if (tid < 128) {
        rp[(size_t)bj * 8192 + bi * 128 + tid] = rbuf[0][tid] + rbuf[1][tid];
        cp[(size_t)bi * 8192 + bj * 128 + tid] = cbuf[0][tid] + cbuf[1][tid];
    }
}

// ---- kernel 3: per-row logs, block partial sums ----
__global__ __launch_bounds__(256) void clip_fin1_k(const float* __restrict__ rp,
                                                   const float* __restrict__ cp,
                                                   const float* __restrict__ dg,
                                                   float* __restrict__ part) {
    int i = blockIdx.x * 256 + threadIdx.x;
    float rs = 0.f, cs = 0.f;
    #pragma unroll 8
    for (int b = 0; b < 64; ++b) {
        rs += rp[(size_t)b * 8192 + i];
        cs += cp[(size_t)b * 8192 + i];
    }
    float c = 0.5f * (logf(rs) + logf(cs)) - dg[i];
    #pragma unroll
    for (int o = 1; o < 64; o <<= 1) c += __shfl_xor(c, o);
    __shared__ float sb[4];
    if ((threadIdx.x & 63) == 0) sb[threadIdx.x >> 6] = c;
    __syncthreads();
    if (threadIdx.x == 0) part[blockIdx.x] = sb[0] + sb[1] + sb[2] + sb[3];
}

// ---- kernel 4: final scalar ----
__global__ void clip_fin2_k(const float* __restrict__ part, float* __restrict__ out) {
    float v = (threadIdx.x < 32) ? part[threadIdx.x] : 0.f;
    #pragma unroll
    for (int o = 1; o < 64; o <<= 1) v += __shfl_xor(v, o);
    if (threadIdx.x == 0) out[0] = v * (1.f / 8192.f);
}

extern "C" void kernel_launch(void* const* d_in, const int* in_sizes, int n_in,
                              void* d_out, int out_size, void* d_ws, size_t ws_size,
                              hipStream_t stream) {
    const float* zi = (const float*)d_in[0];
    const float* zj = (const float*)d_in[1];
    float* out = (float*)d_out;
    char* ws = (char*)d_ws;

    unsigned short* zib = (unsigned short*)(ws);
    unsigned short* zjb = (unsigned short*)(ws + (size_t)16 * 1024 * 1024);
    float* rp   = (float*)(ws + (size_t)32 * 1024 * 1024);
    float* cp   = (float*)(ws + (size_t)34 * 1024 * 1024);
    float* dg   = (float*)(ws + (size_t)36 * 1024 * 1024);
    float* part = (float*)(ws + (size_t)36 * 1024 * 1024 + 32768);

    clip_norm_k<<<8192, 256, 0, stream>>>(zi, zib, 2.0f);   // fold temp (x2) into zi
    clip_norm_k<<<8192, 256, 0, stream>>>(zj, zjb, 1.0f);
    clip_gemm_k<<<4096, 256, 0, stream>>>(zib, zjb, rp, cp, dg);
    clip_fin1_k<<<32, 256, 0, stream>>>(rp, cp, dg, part);
    clip_fin2_k<<<1, 64, 0, stream>>>(part, out);
}

// Round 2
// 202.550 us; speedup vs baseline: 1.2335x; 1.2335x over previous
//
#include <hip/hip_runtime.h>
#include <hip/hip_bf16.h>

// CLIP loss: B=8192, D=1024, temp=0.5.
// loss = mean_i [ 0.5*(log sum_j exp(s_ij) + log sum_j exp(s_ji)) - s_ii ],
// s = (zi_n @ zj_n^T) * 2.  |s| <= 2 -> exp safe, no max trick.
//
// GEMM: 256(M)x128(N) tile, BK=64, 8 waves (4M x 2N), ring-3 LDS double buffer,
// counted vmcnt(12) pipeline (never 0 in steady state), XOR-swizzled LDS
// (pre-swizzled global source + swizzled ds_read), raw s_barrier, setprio.
//
// ws layout (bytes):
//   [0,16M)    zi_bf16 (x2 temp folded)   [16M,32M) zj_bf16
//   [32M,+2M)  rp[64][8192] row-sum partials (per bj)
//   [34M,+1M)  cp[32][8192] col-sum partials (per bi)
//   [36M,+32K) diag[8192]
//   [+32K,..)  block partials

using short8 = __attribute__((ext_vector_type(8))) short;
using f32x4  = __attribute__((ext_vector_type(4))) float;

__device__ __forceinline__ unsigned short f2bf(float f) {
    unsigned int u = __float_as_uint(f);
    unsigned int r = (u + 0x7FFFu + ((u >> 16) & 1u)) >> 16;
    return (unsigned short)r;
}

__device__ __forceinline__ void async16(const unsigned short* g, unsigned short* l) {
    __builtin_amdgcn_global_load_lds(
        (const __attribute__((address_space(1))) void*)g,
        (__attribute__((address_space(3))) void*)l, 16, 0, 0);
}

// ---- kernel 1: row-normalize fp32 -> bf16, extra scale folded ----
__global__ __launch_bounds__(256) void clip_norm_k(const float* __restrict__ in,
                                                   unsigned short* __restrict__ out,
                                                   float extra) {
    int row = blockIdx.x;
    const float4* ip = reinterpret_cast<const float4*>(in + (size_t)row * 1024);
    float4 v = ip[threadIdx.x];
    float ss = v.x * v.x + v.y * v.y + v.z * v.z + v.w * v.w;
    #pragma unroll
    for (int o = 1; o < 64; o <<= 1) ss += __shfl_xor(ss, o);
    __shared__ float sb[4];
    if ((threadIdx.x & 63) == 0) sb[threadIdx.x >> 6] = ss;
    __syncthreads();
    float tot = sb[0] + sb[1] + sb[2] + sb[3];
    float scl = extra / fmaxf(sqrtf(tot), 1e-12f);
    ushort4 o4;
    o4.x = f2bf(v.x * scl);
    o4.y = f2bf(v.y * scl);
    o4.z = f2bf(v.z * scl);
    o4.w = f2bf(v.w * scl);
    *reinterpret_cast<ushort4*>(out + (size_t)row * 1024 + threadIdx.x * 4) = o4;
}

// ---- GEMM with fused exp row/col sums ----
// LDS per tile-slot: A 256x64 (16384 sh) + B 128x64 (8192 sh) = 24576 shorts.
// Physical slot (row, c) holds global k-chunk (c ^ (row&7))  [st-swizzle].

__device__ __forceinline__ void stage_tile(const unsigned short* Ag,
                                           const unsigned short* Bg,
                                           unsigned short* SA, unsigned short* SB,
                                           int kt, int w, int tid) {
    #pragma unroll
    for (int q = 0; q < 4; ++q) {
        int s = q * 512 + tid;
        int row = s >> 3, c = s & 7, cc = c ^ (row & 7);
        async16(Ag + (size_t)row * 1024 + kt + cc * 8, SA + (q * 512 + w * 64) * 8);
    }
    #pragma unroll
    for (int q = 0; q < 2; ++q) {
        int s = q * 512 + tid;
        int row = s >> 3, c = s & 7, cc = c ^ (row & 7);
        async16(Bg + (size_t)row * 1024 + kt + cc * 8, SB + (q * 512 + w * 64) * 8);
    }
}

template<int VMW, bool STG>
__device__ __forceinline__ void kstep(const unsigned short* As, const unsigned short* Bs,
                                      unsigned short* SA, unsigned short* SB,
                                      const unsigned short* Ag, const unsigned short* Bg,
                                      int kt_next, f32x4 (&acc)[4][4],
                                      int wm, int wn, int llo, int lhi, int w, int tid) {
    short8 af[2][4], bf_[2][4];
    #pragma unroll
    for (int kk = 0; kk < 2; ++kk) {
        #pragma unroll
        for (int m = 0; m < 4; ++m) {
            int ra = wm * 64 + m * 16 + llo;
            int c = (kk * 4 + lhi) ^ (ra & 7);
            af[kk][m] = *reinterpret_cast<const short8*>(As + ra * 64 + c * 8);
        }
        #pragma unroll
        for (int n = 0; n < 4; ++n) {
            int rb = wn * 64 + n * 16 + llo;
            int c = (kk * 4 + lhi) ^ (rb & 7);
            bf_[kk][n] = *reinterpret_cast<const short8*>(Bs + rb * 64 + c * 8);
        }
    }
    asm volatile("s_waitcnt lgkmcnt(0)" ::: "memory");
    __builtin_amdgcn_sched_barrier(0);
    __builtin_amdgcn_s_barrier();            // all waves done reading this buf
    __builtin_amdgcn_sched_barrier(0);
    if (STG) stage_tile(Ag, Bg, SA, SB, kt_next, w, tid);
    __builtin_amdgcn_s_setprio(1);
    #pragma unroll
    for (int kk = 0; kk < 2; ++kk)
        #pragma unroll
        for (int m = 0; m < 4; ++m)
            #pragma unroll
            for (int n = 0; n < 4; ++n)
                acc[m][n] = __builtin_amdgcn_mfma_f32_16x16x32_bf16(
                    af[kk][m], bf_[kk][n], acc[m][n], 0, 0, 0);
    __builtin_amdgcn_s_setprio(0);
    __builtin_amdgcn_sched_barrier(0);
    if constexpr (VMW == 12) asm volatile("s_waitcnt vmcnt(12)" ::: "memory");
    else if constexpr (VMW == 6) asm volatile("s_waitcnt vmcnt(6)" ::: "memory");
    else if constexpr (VMW == 0) asm volatile("s_waitcnt vmcnt(0)" ::: "memory");
    if constexpr (VMW >= 0) {
        __builtin_amdgcn_s_barrier();        // next tile landed + all waves past MFMA
        __builtin_amdgcn_sched_barrier(0);
    }
}

__global__ __launch_bounds__(512, 2) void clip_gemm_k(
    const unsigned short* __restrict__ A,   // zi_bf [8192][1024]
    const unsigned short* __restrict__ Bm,  // zj_bf [8192][1024]
    float* __restrict__ rp, float* __restrict__ cp, float* __restrict__ dg) {
    __shared__ unsigned short lds[3 * 24576];   // 147456 B
    __shared__ float rbuf[2][256];
    __shared__ float cbuf[4][128];

    // XCD-aware bijective swizzle: 2048 blocks, 2048 % 8 == 0
    int swz = (blockIdx.x & 7) * 256 + (blockIdx.x >> 3);
    const int bi = swz >> 6;       // 0..31  (M-tile, 256 rows)
    const int bj = swz & 63;       // 0..63  (N-tile, 128 rows of zj)
    const int tid = threadIdx.x;
    const int l = tid & 63, w = tid >> 6;
    const int wm = w >> 1, wn = w & 1;       // 4 x 2 wave grid
    const int lhi = l >> 4, llo = l & 15;

    f32x4 acc[4][4] = {};

    const unsigned short* Ag = A + (size_t)(bi * 256) * 1024;
    const unsigned short* Bg = Bm + (size_t)(bj * 128) * 1024;

    unsigned short* A0 = lds;                unsigned short* B0 = lds + 16384;
    unsigned short* A1 = lds + 24576;        unsigned short* B1 = lds + 24576 + 16384;
    unsigned short* A2 = lds + 49152;        unsigned short* B2 = lds + 49152 + 16384;

    // prologue: stage tiles 0,1,2 into bufs 0,1,2
    stage_tile(Ag, Bg, A0, B0, 0, w, tid);
    stage_tile(Ag, Bg, A1, B1, 64, w, tid);
    stage_tile(Ag, Bg, A2, B2, 128, w, tid);
    asm volatile("s_waitcnt vmcnt(12)" ::: "memory");   // tile 0 landed
    __builtin_amdgcn_s_barrier();
    __builtin_amdgcn_sched_barrier(0);

    // 16 K-tiles; t stages tile t+3 into its own (just-consumed) buffer
    kstep<12, true >(A0, B0, A0, B0, Ag, Bg, 192, acc, wm, wn, llo, lhi, w, tid); // t=0
    kstep<12, true >(A1, B1, A1, B1, Ag, Bg, 256, acc, wm, wn, llo, lhi, w, tid); // t=1
    kstep<12, true >(A2, B2, A2, B2, Ag, Bg, 320, acc, wm, wn, llo, lhi, w, tid); // t=2
    kstep<12, true >(A0, B0, A0, B0, Ag, Bg, 384, acc, wm, wn, llo, lhi, w, tid); // t=3
    kstep<12, true >(A1, B1, A1, B1, Ag, Bg, 448, acc, wm, wn, llo, lhi, w, tid); // t=4
    kstep<12, true >(A2, B2, A2, B2, Ag, Bg, 512, acc, wm, wn, llo, lhi, w, tid); // t=5
    kstep<12, true >(A0, B0, A0, B0, Ag, Bg, 576, acc, wm, wn, llo, lhi, w, tid); // t=6
    kstep<12, true >(A1, B1, A1, B1, Ag, Bg, 640, acc, wm, wn, llo, lhi, w, tid); // t=7
    kstep<12, true >(A2, B2, A2, B2, Ag, Bg, 704, acc, wm, wn, llo, lhi, w, tid); // t=8
    kstep<12, true >(A0, B0, A0, B0, Ag, Bg, 768, acc, wm, wn, llo, lhi, w, tid); // t=9
    kstep<12, true >(A1, B1, A1, B1, Ag, Bg, 832, acc, wm, wn, llo, lhi, w, tid); // t=10
    kstep<12, true >(A2, B2, A2, B2, Ag, Bg, 896, acc, wm, wn, llo, lhi, w, tid); // t=11
    kstep<12, true >(A0, B0, A0, B0, Ag, Bg, 960, acc, wm, wn, llo, lhi, w, tid); // t=12
    kstep<6,  false>(A1, B1, A1, B1, Ag, Bg, 0,   acc, wm, wn, llo, lhi, w, tid); // t=13
    kstep<0,  false>(A2, B2, A2, B2, Ag, Bg, 0,   acc, wm, wn, llo, lhi, w, tid); // t=14
    kstep<-1, false>(A0, B0, A0, B0, Ag, Bg, 0,   acc, wm, wn, llo, lhi, w, tid); // t=15

    // ---- epilogue ----
    // C layout: col = llo, row = lhi*4 + reg (per 16x16 frag)
    // diagonal (pre-exp): tiles overlap iff (bj>>1)==bi
    if ((bj >> 1) == bi) {
        #pragma unroll
        for (int m = 0; m < 4; ++m)
            #pragma unroll
            for (int n = 0; n < 4; ++n)
                #pragma unroll
                for (int r = 0; r < 4; ++r) {
                    int grow = bi * 256 + wm * 64 + m * 16 + lhi * 4 + r;
                    int gcol = bj * 128 + wn * 64 + n * 16 + llo;
                    if (grow == gcol) dg[grow] = acc[m][n][r];
                }
    }

    // exp in place (|s|<=2)
    #pragma unroll
    for (int m = 0; m < 4; ++m)
        #pragma unroll
        for (int n = 0; n < 4; ++n)
            #pragma unroll
            for (int r = 0; r < 4; ++r)
                acc[m][n][r] = exp2f(acc[m][n][r] * 1.44269504f);

    // row sums over this block's 128 cols (this wave: 64 cols -> wn half)
    #pragma unroll
    for (int m = 0; m < 4; ++m) {
        #pragma unroll
        for (int r = 0; r < 4; ++r) {
            float v = acc[m][0][r] + acc[m][1][r] + acc[m][2][r] + acc[m][3][r];
            v += __shfl_xor(v, 1);
            v += __shfl_xor(v, 2);
            v += __shfl_xor(v, 4);
            v += __shfl_xor(v, 8);
            if (llo == 0) rbuf[wn][wm * 64 + m * 16 + lhi * 4 + r] = v;
        }
    }
    // col sums over this block's 256 rows (this wave: its 64 rows -> wm slice)
    #pragma unroll
    for (int n = 0; n < 4; ++n) {
        float v = 0.f;
        #pragma unroll
        for (int m = 0; m < 4; ++m)
            v += acc[m][n][0] + acc[m][n][1] + acc[m][n][2] + acc[m][n][3];
        v += __shfl_xor(v, 16);
        v += __shfl_xor(v, 32);
        if (lhi == 0) cbuf[wm][wn * 64 + n * 16 + llo] = v;
    }
    __syncthreads();
    if (tid < 256) rp[(size_t)bj * 8192 + bi * 256 + tid] = rbuf[0][tid] + rbuf[1][tid];
    if (tid < 128) cp[(size_t)bi * 8192 + bj * 128 + tid] =
        cbuf[0][tid] + cbuf[1][tid] + cbuf[2][tid] + cbuf[3][tid];
}

// ---- per-row logs, block partial sums ----
__global__ __launch_bounds__(256) void clip_fin1_k(const float* __restrict__ rp,
                                                   const float* __restrict__ cp,
                                                   const float* __restrict__ dg,
                                                   float* __restrict__ part) {
    int i = blockIdx.x * 256 + threadIdx.x;
    float rs = 0.f, cs = 0.f;
    #pragma unroll 8
    for (int b = 0; b < 64; ++b) rs += rp[(size_t)b * 8192 + i];
    #pragma unroll 8
    for (int b = 0; b < 32; ++b) cs += cp[(size_t)b * 8192 + i];
    float c = 0.5f * (logf(rs) + logf(cs)) - dg[i];
    #pragma unroll
    for (int o = 1; o < 64; o <<= 1) c += __shfl_xor(c, o);
    __shared__ float sb[4];
    if ((threadIdx.x & 63) == 0) sb[threadIdx.x >> 6] = c;
    __syncthreads();
    if (threadIdx.x == 0) part[blockIdx.x] = sb[0] + sb[1] + sb[2] + sb[3];
}

__global__ void clip_fin2_k(const float* __restrict__ part, float* __restrict__ out) {
    float v = (threadIdx.x < 32) ? part[threadIdx.x] : 0.f;
    #pragma unroll
    for (int o = 1; o < 64; o <<= 1) v += __shfl_xor(v, o);
    if (threadIdx.x == 0) out[0] = v * (1.f / 8192.f);
}

extern "C" void kernel_launch(void* const* d_in, const int* in_sizes, int n_in,
                              void* d_out, int out_size, void* d_ws, size_t ws_size,
                              hipStream_t stream) {
    const float* zi = (const float*)d_in[0];
    const float* zj = (const float*)d_in[1];
    float* out = (float*)d_out;
    char* ws = (char*)d_ws;

    unsigned short* zib = (unsigned short*)(ws);
    unsigned short* zjb = (unsigned short*)(ws + (size_t)16 * 1024 * 1024);
    float* rp   = (float*)(ws + (size_t)32 * 1024 * 1024);
    float* cp   = (float*)(ws + (size_t)34 * 1024 * 1024);
    float* dg   = (float*)(ws + (size_t)36 * 1024 * 1024);
    float* part = (float*)(ws + (size_t)36 * 1024 * 1024 + 32768);

    clip_norm_k<<<8192, 256, 0, stream>>>(zi, zib, 2.0f);   // temp x2 folded into zi
    clip_norm_k<<<8192, 256, 0, stream>>>(zj, zjb, 1.0f);
    clip_gemm_k<<<2048, 512, 0, stream>>>(zib, zjb, rp, cp, dg);
    clip_fin1_k<<<32, 256, 0, stream>>>(rp, cp, dg, part);
    clip_fin2_k<<<1, 64, 0, stream>>>(part, out);
}

// Round 3
// 188.100 us; speedup vs baseline: 1.3282x; 1.0768x over previous
//
#include <hip/hip_runtime.h>
#include <hip/hip_bf16.h>

// CLIP loss: B=8192, D=1024, temp=0.5.
// loss = mean_i [ 0.5*(log sum_j exp(s_ij) + log sum_j exp(s_ji)) - s_ii ],
// s = (zi_n @ zj_n^T) * 2.  |s| <= 2 -> exp safe, no max trick.
//
// GEMM: m201-style 8-phase schedule. BM=BN=256, BK=64 (2 K-halves of 32),
// 512 thr = 8 waves (2M x 4N), per-wave 128x64 output, acc[8][4].
// LDS: A[2dbuf][2kh][256][32] + B[...] = 128 KB. Per phase: {ds_read frags,
// stage 1 chunk (2 gload_lds), barrier, lgkm(0), setprio, 16 MFMA, barrier}.
// Chunk ring: tile t phases 0/1 stage (t+1) khalf1; phases 2/3 stage (t+2)
// khalf0. One vmcnt(4) per tile boundary (vmcnt(0) at the last).
// Swizzle: 16B-chunk c_phys = c_log ^ ((row>>1)&3) -> 2 lanes/bank (free).
//
// ws: [0,16M) zi_bf (x2 temp folded), [16M,32M) zj_bf, [32M,+1M) rp[32][8192],
//     [34M,+1M) cp[32][8192], [36M,+32K) dg[8192], then part[32].

using short8 = __attribute__((ext_vector_type(8))) short;
using f32x4  = __attribute__((ext_vector_type(4))) float;

__device__ __forceinline__ unsigned short f2bf(float f) {
    unsigned int u = __float_as_uint(f);
    unsigned int r = (u + 0x7FFFu + ((u >> 16) & 1u)) >> 16;
    return (unsigned short)r;
}

__device__ __forceinline__ void async16(const unsigned short* g, unsigned short* l) {
    __builtin_amdgcn_global_load_lds(
        (const __attribute__((address_space(1))) void*)g,
        (__attribute__((address_space(3))) void*)l, 16, 0, 0);
}

// ---- kernel 1: row-normalize fp32 -> bf16, extra scale folded ----
__global__ __launch_bounds__(256) void clip_norm_k(const float* __restrict__ in,
                                                   unsigned short* __restrict__ out,
                                                   float extra) {
    int row = blockIdx.x;
    const float4* ip = reinterpret_cast<const float4*>(in + (size_t)row * 1024);
    float4 v = ip[threadIdx.x];
    float ss = v.x * v.x + v.y * v.y + v.z * v.z + v.w * v.w;
    #pragma unroll
    for (int o = 1; o < 64; o <<= 1) ss += __shfl_xor(ss, o);
    __shared__ float sb[4];
    if ((threadIdx.x & 63) == 0) sb[threadIdx.x >> 6] = ss;
    __syncthreads();
    float tot = sb[0] + sb[1] + sb[2] + sb[3];
    float scl = extra / fmaxf(sqrtf(tot), 1e-12f);
    ushort4 o4;
    o4.x = f2bf(v.x * scl);
    o4.y = f2bf(v.y * scl);
    o4.z = f2bf(v.z * scl);
    o4.w = f2bf(v.w * scl);
    *reinterpret_cast<ushort4*>(out + (size_t)row * 1024 + threadIdx.x * 4) = o4;
}

// chunk = [256][32] shorts (16 KB). 2 sweeps x 512 threads x 16B.
// LDS dest linear (wave-uniform base + lane*16); source pre-swizzled.
__device__ __forceinline__ void stage_chunk(const unsigned short* G,
                                            unsigned short* chunk,
                                            int kofs, int tid) {
    #pragma unroll
    for (int s = 0; s < 2; ++s) {
        int idx = s * 512 + tid;
        int row = idx >> 2;
        int clog = (idx & 3) ^ ((row >> 1) & 3);
        async16(G + (size_t)row * 1024 + kofs + clog * 8, chunk + idx * 8);
    }
}

__device__ __forceinline__ short8 ldfrag(const unsigned short* chunk, int row, int lhi) {
    int cphys = lhi ^ ((row >> 1) & 3);
    return *reinterpret_cast<const short8*>(chunk + row * 32 + cphys * 8);
}

__global__ __launch_bounds__(512, 2) void clip_gemm_k(
    const unsigned short* __restrict__ A,   // zi_bf [8192][1024]
    const unsigned short* __restrict__ Bm,  // zj_bf [8192][1024]
    float* __restrict__ rp, float* __restrict__ cp, float* __restrict__ dg) {
    __shared__ unsigned short sh[65536];     // A: [0,32768) B: [32768,65536)
    __shared__ float rbuf[4][256];
    __shared__ float cbuf[2][256];

    // XCD stripe swizzle: 1024 blocks, XCD c gets bj in [4c,4c+4), all bi.
    const int c_x = blockIdx.x & 7, q = blockIdx.x >> 3;
    const int bj = c_x * 4 + (q & 3);        // 0..31
    const int bi = q >> 2;                   // 0..31
    const int tid = threadIdx.x;
    const int l = tid & 63, w = tid >> 6;
    const int wm = w >> 2, wn = w & 3;       // 2M x 4N wave grid
    const int lhi = l >> 4, llo = l & 15;

    f32x4 acc[8][4] = {};

    const unsigned short* Ag = A + (size_t)(bi * 256) * 1024;
    const unsigned short* Bg = Bm + (size_t)(bj * 256) * 1024;

    unsigned short* As_ = sh;            // [db][kh][256][32]
    unsigned short* Bs_ = sh + 32768;

    // prologue: t0.A0,t0.B0,t0.A1,t0.B1,t1.A0,t1.B0 then vmcnt(4)=t0 landed
    stage_chunk(Ag, As_ + 0 * 8192, 0, tid);
    stage_chunk(Bg, Bs_ + 0 * 8192, 0, tid);
    stage_chunk(Ag, As_ + 1 * 8192, 32, tid);
    stage_chunk(Bg, Bs_ + 1 * 8192, 32, tid);
    stage_chunk(Ag, As_ + 2 * 8192, 64, tid);
    stage_chunk(Bg, Bs_ + 2 * 8192, 64, tid);
    asm volatile("s_waitcnt vmcnt(4)" ::: "memory");
    __builtin_amdgcn_s_barrier();
    __builtin_amdgcn_sched_barrier(0);

    short8 af[4], bf_[4];

#define MFMA_Q(MH)                                                        \
    __builtin_amdgcn_s_setprio(1);                                        \
    _Pragma("unroll") for (int m = 0; m < 4; ++m)                         \
    _Pragma("unroll") for (int n = 0; n < 4; ++n)                         \
        acc[(MH)*4+m][n] = __builtin_amdgcn_mfma_f32_16x16x32_bf16(       \
            af[m], bf_[n], acc[(MH)*4+m][n], 0, 0, 0);                    \
    __builtin_amdgcn_s_setprio(0);                                        \
    __builtin_amdgcn_sched_barrier(0);

    for (int t = 0; t < 16; ++t) {
        const int db = t & 1;
        const unsigned short* Ak0 = As_ + (db * 2 + 0) * 8192;
        const unsigned short* Ak1 = As_ + (db * 2 + 1) * 8192;
        const unsigned short* Bk0 = Bs_ + (db * 2 + 0) * 8192;
        const unsigned short* Bk1 = Bs_ + (db * 2 + 1) * 8192;
        unsigned short* nA1 = As_ + (((t + 1) & 1) * 2 + 1) * 8192;  // (t+1) khalf1
        unsigned short* nB1 = Bs_ + (((t + 1) & 1) * 2 + 1) * 8192;
        unsigned short* nA0 = As_ + (db * 2 + 0) * 8192;             // (t+2) khalf0
        unsigned short* nB0 = Bs_ + (db * 2 + 0) * 8192;

        // ---- phase 0: kk0, mh0 (reads B kk0 too); stage (t+1).A1 ----
        #pragma unroll
        for (int m = 0; m < 4; ++m) af[m] = ldfrag(Ak0, wm * 128 + m * 16 + llo, lhi);
        #pragma unroll
        for (int n = 0; n < 4; ++n) bf_[n] = ldfrag(Bk0, wn * 64 + n * 16 + llo, lhi);
        if (t <= 14) stage_chunk(Ag, nA1, (t + 1) * 64 + 32, tid);
        __builtin_amdgcn_s_barrier();
        asm volatile("s_waitcnt lgkmcnt(0)" ::: "memory");
        __builtin_amdgcn_sched_barrier(0);
        MFMA_Q(0)
        __builtin_amdgcn_s_barrier();

        // ---- phase 1: kk0, mh1 (B reused); stage (t+1).B1 ----
        #pragma unroll
        for (int m = 0; m < 4; ++m) af[m] = ldfrag(Ak0, wm * 128 + 64 + m * 16 + llo, lhi);
        if (t <= 14) stage_chunk(Bg, nB1, (t + 1) * 64 + 32, tid);
        __builtin_amdgcn_s_barrier();
        asm volatile("s_waitcnt lgkmcnt(0)" ::: "memory");
        __builtin_amdgcn_sched_barrier(0);
        MFMA_Q(1)
        __builtin_amdgcn_s_barrier();

        // ---- phase 2: kk1, mh0 (reads B kk1); stage (t+2).A0 ----
        #pragma unroll
        for (int m = 0; m < 4; ++m) af[m] = ldfrag(Ak1, wm * 128 + m * 16 + llo, lhi);
        #pragma unroll
        for (int n = 0; n < 4; ++n) bf_[n] = ldfrag(Bk1, wn * 64 + n * 16 + llo, lhi);
        if (t <= 13) stage_chunk(Ag, nA0, (t + 2) * 64, tid);
        __builtin_amdgcn_s_barrier();
        asm volatile("s_waitcnt lgkmcnt(0)" ::: "memory");
        __builtin_amdgcn_sched_barrier(0);
        MFMA_Q(0)
        __builtin_amdgcn_s_barrier();

        // ---- phase 3: kk1, mh1 (B reused); stage (t+2).B0; boundary wait ----
        #pragma unroll
        for (int m = 0; m < 4; ++m) af[m] = ldfrag(Ak1, wm * 128 + 64 + m * 16 + llo, lhi);
        if (t <= 13) stage_chunk(Bg, nB0, (t + 2) * 64, tid);
        __builtin_amdgcn_s_barrier();
        asm volatile("s_waitcnt lgkmcnt(0)" ::: "memory");
        __builtin_amdgcn_sched_barrier(0);
        MFMA_Q(1)
        if (t <= 13)      asm volatile("s_waitcnt vmcnt(4)" ::: "memory");
        else if (t == 14) asm volatile("s_waitcnt vmcnt(0)" ::: "memory");
        __builtin_amdgcn_s_barrier();
    }
#undef MFMA_Q

    // ---- epilogue ----
    // C frag layout: col = llo, row = lhi*4 + reg.
    // wave output: rows bi*256 + wm*128 + m*16 + lhi*4 + r (m 0..7),
    //              cols bj*256 + wn*64 + n*16 + llo (n 0..3)
    if (bi == bj) {
        #pragma unroll
        for (int m = 0; m < 8; ++m)
            #pragma unroll
            for (int n = 0; n < 4; ++n)
                #pragma unroll
                for (int r = 0; r < 4; ++r) {
                    int lrow = wm * 128 + m * 16 + lhi * 4 + r;
                    int lcol = wn * 64 + n * 16 + llo;
                    if (lrow == lcol) dg[bi * 256 + lrow] = acc[m][n][r];
                }
    }

    #pragma unroll
    for (int m = 0; m < 8; ++m)
        #pragma unroll
        for (int n = 0; n < 4; ++n)
            #pragma unroll
            for (int r = 0; r < 4; ++r)
                acc[m][n][r] = exp2f(acc[m][n][r] * 1.44269504f);

    // row sums (this wave's 64 cols); reduce over llo then across wn via LDS
    #pragma unroll
    for (int m = 0; m < 8; ++m) {
        #pragma unroll
        for (int r = 0; r < 4; ++r) {
            float v = acc[m][0][r] + acc[m][1][r] + acc[m][2][r] + acc[m][3][r];
            v += __shfl_xor(v, 1);
            v += __shfl_xor(v, 2);
            v += __shfl_xor(v, 4);
            v += __shfl_xor(v, 8);
            if (llo == 0) rbuf[wn][wm * 128 + m * 16 + lhi * 4 + r] = v;
        }
    }
    // col sums (this wave's 128 rows); reduce over lhi then across wm via LDS
    #pragma unroll
    for (int n = 0; n < 4; ++n) {
        float v = 0.f;
        #pragma unroll
        for (int m = 0; m < 8; ++m)
            v += acc[m][n][0] + acc[m][n][1] + acc[m][n][2] + acc[m][n][3];
        v += __shfl_xor(v, 16);
        v += __shfl_xor(v, 32);
        if (lhi == 0) cbuf[wm][wn * 64 + n * 16 + llo] = v;
    }
    __syncthreads();
    if (tid < 256) {
        rp[(size_t)bj * 8192 + bi * 256 + tid] =
            rbuf[0][tid] + rbuf[1][tid] + rbuf[2][tid] + rbuf[3][tid];
        cp[(size_t)bi * 8192 + bj * 256 + tid] = cbuf[0][tid] + cbuf[1][tid];
    }
}

// ---- per-row logs, block partial sums ----
__global__ __launch_bounds__(256) void clip_fin1_k(const float* __restrict__ rp,
                                                   const float* __restrict__ cp,
                                                   const float* __restrict__ dg,
                                                   float* __restrict__ part) {
    int i = blockIdx.x * 256 + threadIdx.x;
    float rs = 0.f, cs = 0.f;
    #pragma unroll 8
    for (int b = 0; b < 32; ++b) rs += rp[(size_t)b * 8192 + i];
    #pragma unroll 8
    for (int b = 0; b < 32; ++b) cs += cp[(size_t)b * 8192 + i];
    float c = 0.5f * (logf(rs) + logf(cs)) - dg[i];
    #pragma unroll
    for (int o = 1; o < 64; o <<= 1) c += __shfl_xor(c, o);
    __shared__ float sb[4];
    if ((threadIdx.x & 63) == 0) sb[threadIdx.x >> 6] = c;
    __syncthreads();
    if (threadIdx.x == 0) part[blockIdx.x] = sb[0] + sb[1] + sb[2] + sb[3];
}

__global__ void clip_fin2_k(const float* __restrict__ part, float* __restrict__ out) {
    float v = (threadIdx.x < 32) ? part[threadIdx.x] : 0.f;
    #pragma unroll
    for (int o = 1; o < 64; o <<= 1) v += __shfl_xor(v, o);
    if (threadIdx.x == 0) out[0] = v * (1.f / 8192.f);
}

extern "C" void kernel_launch(void* const* d_in, const int* in_sizes, int n_in,
                              void* d_out, int out_size, void* d_ws, size_t ws_size,
                              hipStream_t stream) {
    const float* zi = (const float*)d_in[0];
    const float* zj = (const float*)d_in[1];
    float* out = (float*)d_out;
    char* ws = (char*)d_ws;

    unsigned short* zib = (unsigned short*)(ws);
    unsigned short* zjb = (unsigned short*)(ws + (size_t)16 * 1024 * 1024);
    float* rp   = (float*)(ws + (size_t)32 * 1024 * 1024);
    float* cp   = (float*)(ws + (size_t)34 * 1024 * 1024);
    float* dg   = (float*)(ws + (size_t)36 * 1024 * 1024);
    float* part = (float*)(ws + (size_t)36 * 1024 * 1024 + 32768);

    clip_norm_k<<<8192, 256, 0, stream>>>(zi, zib, 2.0f);   // temp x2 folded into zi
    clip_norm_k<<<8192, 256, 0, stream>>>(zj, zjb, 1.0f);
    clip_gemm_k<<<1024, 512, 0, stream>>>(zib, zjb, rp, cp, dg);
    clip_fin1_k<<<32, 256, 0, stream>>>(rp, cp, dg, part);
    clip_fin2_k<<<1, 64, 0, stream>>>(part, out);
}